// Round 11
// baseline (169.981 us; speedup 1.0000x reference)
//
#include <hip/hip_runtime.h>
#include <hip/hip_bf16.h>
#include <math.h>

#define B_ 16
#define A_ 256
#define N_ 64
#define G_ 64
#define F_ 128
#define APB 8   // atoms per block (cfconv); grid = 4096/APB = 512 = 2 blocks/CU

typedef __attribute__((ext_vector_type(8))) short short8;
typedef __attribute__((ext_vector_type(4))) float floatx4;

__device__ __forceinline__ float ssp(float x) {
    // shifted softplus via native v_exp_f32 / v_log_f32
    const float t = __expf(-fabsf(x));
    return fmaxf(x, 0.0f) + __logf(1.0f + t) - 0.69314718055994531f;
}
// branch-free RNE fp32->bf16 (finite inputs only)
__device__ __forceinline__ unsigned f2bf(float f) {
    union { float f; unsigned u; } v; v.f = f;
    v.u += 0x7fffu + ((v.u >> 16) & 1u);
    return v.u >> 16;
}
__device__ __forceinline__ float bf2f_lo(unsigned d) {
    union { unsigned i; float f; } v; v.i = d << 16; return v.f;
}
__device__ __forceinline__ float bf2f_hi(unsigned d) {
    union { unsigned i; float f; } v; v.i = d & 0xffff0000u; return v.f;
}
__device__ __forceinline__ short8 pack_bf8(const float4& v0, const float4& v1) {
    short8 t;
    t[0] = (short)f2bf(v0.x); t[1] = (short)f2bf(v0.y);
    t[2] = (short)f2bf(v0.z); t[3] = (short)f2bf(v0.w);
    t[4] = (short)f2bf(v1.x); t[5] = (short)f2bf(v1.y);
    t[6] = (short)f2bf(v1.z); t[7] = (short)f2bf(v1.w);
    return t;
}

// ---------------------------------------------------------------------------
// K0: repack all four weights into MFMA B-frag order (bf16).
// frag layout [tf][ks][lane(64)][j(8)]: k = ks*32+(lane>>4)*8+j, f = tf*16+(lane&15)
__global__ __launch_bounds__(256) void k0_repack(
    const float* __restrict__ fw1, const float* __restrict__ fw2,
    const float* __restrict__ win, const float* __restrict__ wout,
    unsigned short* __restrict__ fw1B, unsigned short* __restrict__ fw2B,
    unsigned short* __restrict__ winB, unsigned short* __restrict__ woutB)
{
    int idx = blockIdx.x * 1024 + threadIdx.x * 4;
    #pragma unroll
    for (int u = 0; u < 4; ++u, ++idx) {
        if (idx < 8192) {                         // fw1: K=64
            const int j  = idx & 7;
            const int l  = (idx >> 3) & 63;
            const int ks = (idx >> 9) & 1;
            const int tf = idx >> 10;
            const int g  = ks * 32 + (l >> 4) * 8 + j;
            const int f  = tf * 16 + (l & 15);
            fw1B[idx] = (unsigned short)f2bf(fw1[g * F_ + f]);
        } else {                                  // K=128 packs
            const int i2  = (idx - 8192) & 16383;
            const int sel = (idx - 8192) >> 14;   // 0: fw2, 1: win, 2: wout
            const int j  = i2 & 7;
            const int l  = (i2 >> 3) & 63;
            const int ks = (i2 >> 9) & 3;
            const int tf = i2 >> 11;
            const int k  = ks * 32 + (l >> 4) * 8 + j;
            const int f  = tf * 16 + (l & 15);
            const float v = (sel == 0) ? fw2[k * F_ + f]
                          : (sel == 1) ? win[k * F_ + f]
                                       : wout[k * F_ + f];
            unsigned short* dst = (sel == 0) ? fw2B : (sel == 1) ? winB : woutB;
            dst[i2] = (unsigned short)f2bf(v);
        }
    }
}

// ---------------------------------------------------------------------------
// K1: ypre = bf16(x @ w_in2f), PERMUTED layout ypre[a*128 + c0*8 + tf]
__global__ __launch_bounds__(256) void in2f_gemm(
    const float* __restrict__ x, const unsigned short* __restrict__ winB,
    unsigned short* __restrict__ ypre)
{
    const int tid = threadIdx.x;
    const int w = tid >> 6, l = tid & 63, quad = l >> 4, c0 = l & 15;
    const int row = blockIdx.x * 64 + w * 16 + c0;

    short8 a[4];
    {
        const float* base = x + (size_t)row * F_ + quad * 8;
        #pragma unroll
        for (int ks = 0; ks < 4; ++ks)
            a[ks] = pack_bf8(*(const float4*)(base + ks * 32),
                             *(const float4*)(base + ks * 32 + 4));
    }

    const short8* W8 = (const short8*)winB;
    floatx4 acc[8];
    #pragma unroll
    for (int tf = 0; tf < 8; ++tf) acc[tf] = (floatx4){0.f,0.f,0.f,0.f};
    #pragma unroll
    for (int ks = 0; ks < 4; ++ks)
        #pragma unroll
        for (int tf = 0; tf < 8; ++tf)
            acc[tf] = __builtin_amdgcn_mfma_f32_16x16x32_bf16(
                a[ks], W8[(tf * 4 + ks) * 64 + l], acc[tf], 0, 0, 0);

    #pragma unroll
    for (int r = 0; r < 4; ++r) {
        const int ro = blockIdx.x * 64 + w * 16 + quad * 4 + r;
        short8 s;
        #pragma unroll
        for (int tf = 0; tf < 8; ++tf) s[tf] = (short)f2bf(acc[tf][r]);
        *(short8*)&ypre[(size_t)ro * F_ + c0 * 8] = s;
    }
}

// ---------------------------------------------------------------------------
// K2: persistent block, 512 threads = 8 waves, APB atoms per block.
// EXACT round-9 structure (proven 47.2 us) with ONE change: biases folded
// into the MFMA accumulator init (removes 32 v_add per atom per lane).
__global__ __launch_bounds__(512) void cfconv_kernel(
    const float* __restrict__ r_ij, const float* __restrict__ f_ij,
    const int*   __restrict__ nbrs, const float* __restrict__ mask,
    const float* __restrict__ fb1,  const float* __restrict__ fb2,
    const unsigned short* __restrict__ ypre,
    const unsigned short* __restrict__ fw1B,
    const unsigned short* __restrict__ fw2B,
    unsigned short* __restrict__ y_agg)
{
    __shared__ unsigned short s_w[24576];  // 48 KB: fw1B | fw2B frags
    __shared__ short s_h1[N_ * F_];        // 16 KB, XOR-chunk swizzle
    __shared__ float s_scale[2][N_];
    __shared__ int   s_nb[2][N_];
    __shared__ float s_red[4][F_];

    const int tid  = threadIdx.x;
    const int w    = tid >> 6;
    const int l    = tid & 63;
    const int quad = l >> 4;
    const int c0   = l & 15;
    const int rw   = w & 3;               // row group
    const int h    = w >> 2;              // tf half

    const int abase = blockIdx.x * APB;   // APB-aligned -> same molecule
    const int b     = abase >> 8;

    // ---- stage weights into LDS (once): 6 x uint4 per thread ----
    {
        const uint4* w1 = (const uint4*)fw1B;   // 1024 uint4
        const uint4* w2 = (const uint4*)fw2B;   // 2048 uint4
        uint4* dst = (uint4*)s_w;
        #pragma unroll
        for (int i = 0; i < 6; ++i) {
            const int idx = tid + i * 512;
            dst[idx] = (idx < 1024) ? w1[idx] : w2[idx - 1024];
        }
    }
    // ---- meta for atom 0 ----
    if (h == 0 && l < 16) {
        const int n = rw * 16 + l;
        const float r = r_ij[(size_t)abase * N_ + n];
        const float c = (r < 5.0f)
            ? 0.5f * (__cosf(r * 0.62831853071795865f) + 1.0f)
            : 0.0f;
        s_scale[0][n] = c * mask[(size_t)abase * N_ + n];
        s_nb[0][n]    = nbrs[(size_t)abase * N_ + n];
    }
    // ---- A-tile prefetch for atom 0 ----
    float4 pf[4];
    {
        const float* base = f_ij + (size_t)abase * (N_ * G_)
                          + (size_t)(rw * 16 + c0) * G_ + quad * 8;
        pf[0] = *(const float4*)(base);
        pf[1] = *(const float4*)(base + 4);
        pf[2] = *(const float4*)(base + 32);
        pf[3] = *(const float4*)(base + 36);
    }
    // hoisted biases (per-lane, loop-invariant)
    float fb1v[4], fb2v[4];
    #pragma unroll
    for (int t = 0; t < 4; ++t) {
        fb1v[t] = fb1[(h * 4 + t) * 16 + c0];
        fb2v[t] = fb2[(h * 4 + t) * 16 + c0];
    }
    __syncthreads();   // weights + meta(0) staged

    const short8* sw1 = (const short8*)s_w;            // 16 frags
    const short8* sw2 = (const short8*)(s_w + 8192);   // 32 frags
    const unsigned short* yb = ypre + (size_t)b * A_ * F_;

    for (int i = 0; i < APB; ++i) {
        const int atom = abase + i;
        const int buf  = i & 1;

        // convert prefetched A-tile to frags
        short8 a1[2];
        a1[0] = pack_bf8(pf[0], pf[1]);
        a1[1] = pack_bf8(pf[2], pf[3]);

        // ---- GEMM1 (half): h1[:, h*64 .. h*64+64), fb1 in acc init ----
        floatx4 acc1[4];
        #pragma unroll
        for (int t = 0; t < 4; ++t)
            acc1[t] = (floatx4){fb1v[t], fb1v[t], fb1v[t], fb1v[t]};
        #pragma unroll
        for (int ks = 0; ks < 2; ++ks)
            #pragma unroll
            for (int t = 0; t < 4; ++t) {
                const int tf = h * 4 + t;
                acc1[t] = __builtin_amdgcn_mfma_f32_16x16x32_bf16(
                    a1[ks], sw1[(tf * 2 + ks) * 64 + l], acc1[t], 0, 0, 0);
            }

        // ---- prefetch atom i+1 (loads stay in flight across barriers) ----
        if (i + 1 < APB) {
            const float* base = f_ij + (size_t)(atom + 1) * (N_ * G_)
                              + (size_t)(rw * 16 + c0) * G_ + quad * 8;
            pf[0] = *(const float4*)(base);
            pf[1] = *(const float4*)(base + 4);
            pf[2] = *(const float4*)(base + 32);
            pf[3] = *(const float4*)(base + 36);
            if (h == 0 && l < 16) {
                const int n = rw * 16 + l;
                const float r = r_ij[(size_t)(atom + 1) * N_ + n];
                const float c = (r < 5.0f)
                    ? 0.5f * (__cosf(r * 0.62831853071795865f) + 1.0f)
                    : 0.0f;
                s_scale[buf ^ 1][n] = c * mask[(size_t)(atom + 1) * N_ + n];
                s_nb[buf ^ 1][n]    = nbrs[(size_t)(atom + 1) * N_ + n];
            }
        }

        // ---- ssp -> s_h1 (bf16, chunk-XOR swizzle) ----
        #pragma unroll
        for (int t = 0; t < 4; ++t) {
            const int   tf    = h * 4 + t;
            const int   chunk = tf * 2 + (c0 >> 3);
            const int   o     = c0 & 7;
            #pragma unroll
            for (int r = 0; r < 4; ++r) {
                const int row_l = quad * 4 + r;
                const float v = ssp(acc1[t][r]);
                s_h1[(rw * 16 + row_l) * F_ + ((chunk ^ row_l) * 8) + o] =
                    (short)f2bf(v);
            }
        }
        __syncthreads();   // h1 ready

        // ---- GEMM2 (half) + gather ----
        short8 a2[4];
        #pragma unroll
        for (int ks = 0; ks < 4; ++ks)
            a2[ks] = *(const short8*)&s_h1[(rw * 16 + c0) * F_
                                           + (((ks * 4 + quad) ^ c0) * 8)];

        float scl[4];
        uint2 yv[4];
        #pragma unroll
        for (int r = 0; r < 4; ++r) {
            const int n = rw * 16 + quad * 4 + r;
            scl[r] = s_scale[buf][n];
            yv[r] = *(const uint2*)&yb[(size_t)s_nb[buf][n] * F_
                                       + c0 * 8 + h * 4];
        }

        floatx4 acc2[4];
        #pragma unroll
        for (int t = 0; t < 4; ++t)
            acc2[t] = (floatx4){fb2v[t], fb2v[t], fb2v[t], fb2v[t]};
        #pragma unroll
        for (int ks = 0; ks < 4; ++ks)
            #pragma unroll
            for (int t = 0; t < 4; ++t) {
                const int tf = h * 4 + t;
                acc2[t] = __builtin_amdgcn_mfma_f32_16x16x32_bf16(
                    a2[ks], sw2[(tf * 4 + ks) * 64 + l], acc2[t], 0, 0, 0);
            }

        // ---- aggregate (fb2 already in acc2) ----
        float part[4];
        #pragma unroll
        for (int t = 0; t < 4; ++t) part[t] = 0.0f;
        #pragma unroll
        for (int r = 0; r < 4; ++r) {
            const unsigned d0 = yv[r].x, d1 = yv[r].y;
            part[0] = fmaf(acc2[0][r] * scl[r], bf2f_lo(d0), part[0]);
            part[1] = fmaf(acc2[1][r] * scl[r], bf2f_hi(d0), part[1]);
            part[2] = fmaf(acc2[2][r] * scl[r], bf2f_lo(d1), part[2]);
            part[3] = fmaf(acc2[3][r] * scl[r], bf2f_hi(d1), part[3]);
        }
        #pragma unroll
        for (int t = 0; t < 4; ++t) {
            part[t] += __shfl_xor(part[t], 16, 64);
            part[t] += __shfl_xor(part[t], 32, 64);
        }
        if (l < 16) {
            #pragma unroll
            for (int t = 0; t < 4; ++t)
                s_red[rw][(h * 4 + t) * 16 + l] = part[t];
        }
        __syncthreads();   // s_red ready

        if (tid < F_) {
            const float v = s_red[0][tid] + s_red[1][tid]
                          + s_red[2][tid] + s_red[3][tid];
            y_agg[(size_t)atom * F_ + tid] = (unsigned short)f2bf(v);
        }
        // next iteration's s_h1/s_red writes are separated from this
        // iteration's reads by the next h1-ready barrier.
    }
}

// ---------------------------------------------------------------------------
// K3: out = ssp(y_agg @ w_f2out + b_f2out). 64 blocks x 64 rows.
__global__ __launch_bounds__(256) void f2out_kernel(
    const unsigned short* __restrict__ y_agg,
    const unsigned short* __restrict__ woutB,
    const float* __restrict__ bias, float* __restrict__ out)
{
    const int tid = threadIdx.x;
    const int w = tid >> 6, l = tid & 63, quad = l >> 4, c0 = l & 15;
    const int row = blockIdx.x * 64 + w * 16 + c0;

    short8 a[4];
    #pragma unroll
    for (int ks = 0; ks < 4; ++ks)
        a[ks] = *(const short8*)&y_agg[(size_t)row * F_ + ks * 32 + quad * 8];

    const short8* W8 = (const short8*)woutB;
    floatx4 acc[8];
    #pragma unroll
    for (int tf = 0; tf < 8; ++tf) {
        const float bs = bias[tf * 16 + c0];
        acc[tf] = (floatx4){bs, bs, bs, bs};
    }
    #pragma unroll
    for (int ks = 0; ks < 4; ++ks)
        #pragma unroll
        for (int tf = 0; tf < 8; ++tf)
            acc[tf] = __builtin_amdgcn_mfma_f32_16x16x32_bf16(
                a[ks], W8[(tf * 4 + ks) * 64 + l], acc[tf], 0, 0, 0);

    #pragma unroll
    for (int tf = 0; tf < 8; ++tf) {
        #pragma unroll
        for (int r = 0; r < 4; ++r) {
            const int ro = blockIdx.x * 64 + w * 16 + quad * 4 + r;
            out[(size_t)ro * F_ + tf * 16 + c0] = ssp(acc[tf][r]);
        }
    }
}

// ---------------------------------------------------------------------------
extern "C" void kernel_launch(void* const* d_in, const int* in_sizes, int n_in,
                              void* d_out, int out_size, void* d_ws, size_t ws_size,
                              hipStream_t stream) {
    const float* x        = (const float*)d_in[0];
    const float* r_ij     = (const float*)d_in[1];
    const float* f_ij     = (const float*)d_in[2];
    const int*   nbrs     = (const int*)  d_in[3];
    const float* mask     = (const float*)d_in[4];
    const float* fw1      = (const float*)d_in[5];
    const float* fb1      = (const float*)d_in[6];
    const float* fw2      = (const float*)d_in[7];
    const float* fb2      = (const float*)d_in[8];
    const float* w_in2f   = (const float*)d_in[9];
    const float* w_f2out  = (const float*)d_in[10];
    const float* b_f2out  = (const float*)d_in[11];
    float* out = (float*)d_out;

    // ws (shorts): ypre | fw1B | fw2B | winB | woutB | y_agg
    unsigned short* ypre  = (unsigned short*)d_ws;
    unsigned short* fw1B  = ypre  + (size_t)B_ * A_ * F_;   // 524288
    unsigned short* fw2B  = fw1B  + 8192;
    unsigned short* winB  = fw2B  + 16384;
    unsigned short* woutB = winB  + 16384;
    unsigned short* y_agg = woutB + 16384;

    k0_repack<<<56, 256, 0, stream>>>(
        fw1, fw2, w_in2f, w_f2out, fw1B, fw2B, winB, woutB);
    in2f_gemm<<<B_ * A_ / 64, 256, 0, stream>>>(x, winB, ypre);
    cfconv_kernel<<<B_ * A_ / APB, 512, 0, stream>>>(
        r_ij, f_ij, nbrs, mask, fb1, fb2, ypre, fw1B, fw2B, y_agg);
    f2out_kernel<<<B_ * A_ / 64, 256, 0, stream>>>(y_agg, woutB, b_f2out, out);
}

// Round 12
// 157.107 us; speedup vs baseline: 1.0819x; 1.0819x over previous
//
#include <hip/hip_runtime.h>
#include <hip/hip_bf16.h>
#include <math.h>

#define B_ 16
#define A_ 256
#define N_ 64
#define G_ 64
#define F_ 128
#define APB 8   // atoms per block (cfconv); grid = 4096/APB = 512 = 2 blocks/CU

typedef __attribute__((ext_vector_type(8))) short short8;
typedef __attribute__((ext_vector_type(4))) float floatx4;

__device__ __forceinline__ float ssp(float x) {
    // shifted softplus via native v_exp_f32 / v_log_f32
    const float t = __expf(-fabsf(x));
    return fmaxf(x, 0.0f) + __logf(1.0f + t) - 0.69314718055994531f;
}
// branch-free RNE fp32->bf16 (finite inputs only)
__device__ __forceinline__ unsigned f2bf(float f) {
    union { float f; unsigned u; } v; v.f = f;
    v.u += 0x7fffu + ((v.u >> 16) & 1u);
    return v.u >> 16;
}
__device__ __forceinline__ float bf2f_lo(unsigned d) {
    union { unsigned i; float f; } v; v.i = d << 16; return v.f;
}
__device__ __forceinline__ float bf2f_hi(unsigned d) {
    union { unsigned i; float f; } v; v.i = d & 0xffff0000u; return v.f;
}
__device__ __forceinline__ short8 pack_bf8(const float4& v0, const float4& v1) {
    short8 t;
    t[0] = (short)f2bf(v0.x); t[1] = (short)f2bf(v0.y);
    t[2] = (short)f2bf(v0.z); t[3] = (short)f2bf(v0.w);
    t[4] = (short)f2bf(v1.x); t[5] = (short)f2bf(v1.y);
    t[6] = (short)f2bf(v1.z); t[7] = (short)f2bf(v1.w);
    return t;
}

// ---------------------------------------------------------------------------
// K0: repack all four weights into MFMA B-frag order (bf16).
// frag layout [tf][ks][lane(64)][j(8)]: k = ks*32+(lane>>4)*8+j, f = tf*16+(lane&15)
__global__ __launch_bounds__(256) void k0_repack(
    const float* __restrict__ fw1, const float* __restrict__ fw2,
    const float* __restrict__ win, const float* __restrict__ wout,
    unsigned short* __restrict__ fw1B, unsigned short* __restrict__ fw2B,
    unsigned short* __restrict__ winB, unsigned short* __restrict__ woutB)
{
    int idx = blockIdx.x * 1024 + threadIdx.x * 4;
    #pragma unroll
    for (int u = 0; u < 4; ++u, ++idx) {
        if (idx < 8192) {                         // fw1: K=64
            const int j  = idx & 7;
            const int l  = (idx >> 3) & 63;
            const int ks = (idx >> 9) & 1;
            const int tf = idx >> 10;
            const int g  = ks * 32 + (l >> 4) * 8 + j;
            const int f  = tf * 16 + (l & 15);
            fw1B[idx] = (unsigned short)f2bf(fw1[g * F_ + f]);
        } else {                                  // K=128 packs
            const int i2  = (idx - 8192) & 16383;
            const int sel = (idx - 8192) >> 14;   // 0: fw2, 1: win, 2: wout
            const int j  = i2 & 7;
            const int l  = (i2 >> 3) & 63;
            const int ks = (i2 >> 9) & 3;
            const int tf = i2 >> 11;
            const int k  = ks * 32 + (l >> 4) * 8 + j;
            const int f  = tf * 16 + (l & 15);
            const float v = (sel == 0) ? fw2[k * F_ + f]
                          : (sel == 1) ? win[k * F_ + f]
                                       : wout[k * F_ + f];
            unsigned short* dst = (sel == 0) ? fw2B : (sel == 1) ? winB : woutB;
            dst[i2] = (unsigned short)f2bf(v);
        }
    }
}

// ---------------------------------------------------------------------------
// K1: ypre = bf16(x @ w_in2f), PERMUTED layout ypre[a*128 + c0*8 + tf]
__global__ __launch_bounds__(256) void in2f_gemm(
    const float* __restrict__ x, const unsigned short* __restrict__ winB,
    unsigned short* __restrict__ ypre)
{
    const int tid = threadIdx.x;
    const int w = tid >> 6, l = tid & 63, quad = l >> 4, c0 = l & 15;
    const int row = blockIdx.x * 64 + w * 16 + c0;

    short8 a[4];
    {
        const float* base = x + (size_t)row * F_ + quad * 8;
        #pragma unroll
        for (int ks = 0; ks < 4; ++ks)
            a[ks] = pack_bf8(*(const float4*)(base + ks * 32),
                             *(const float4*)(base + ks * 32 + 4));
    }

    const short8* W8 = (const short8*)winB;
    floatx4 acc[8];
    #pragma unroll
    for (int tf = 0; tf < 8; ++tf) acc[tf] = (floatx4){0.f,0.f,0.f,0.f};
    #pragma unroll
    for (int ks = 0; ks < 4; ++ks)
        #pragma unroll
        for (int tf = 0; tf < 8; ++tf)
            acc[tf] = __builtin_amdgcn_mfma_f32_16x16x32_bf16(
                a[ks], W8[(tf * 4 + ks) * 64 + l], acc[tf], 0, 0, 0);

    #pragma unroll
    for (int r = 0; r < 4; ++r) {
        const int ro = blockIdx.x * 64 + w * 16 + quad * 4 + r;
        short8 s;
        #pragma unroll
        for (int tf = 0; tf < 8; ++tf) s[tf] = (short)f2bf(acc[tf][r]);
        *(short8*)&ypre[(size_t)ro * F_ + c0 * 8] = s;
    }
}

// ---------------------------------------------------------------------------
// K2: persistent block, 512 threads = 8 waves, APB atoms per block.
// Weights staged in LDS once; per-atom pipeline keeps next atom's f_ij +
// metadata loads in flight across both barriers (cp.async-style overlap).
// NOTE: this is the round-9 kernel, byte-for-byte (best measured: 47.2 us).
// Rounds 10/11 showed the acc-init and load ordering here are load-bearing:
// bias-folded acc init regressed 30% (forces accvgpr writes from live VGPRs).
__global__ __launch_bounds__(512) void cfconv_kernel(
    const float* __restrict__ r_ij, const float* __restrict__ f_ij,
    const int*   __restrict__ nbrs, const float* __restrict__ mask,
    const float* __restrict__ fb1,  const float* __restrict__ fb2,
    const unsigned short* __restrict__ ypre,
    const unsigned short* __restrict__ fw1B,
    const unsigned short* __restrict__ fw2B,
    unsigned short* __restrict__ y_agg)
{
    __shared__ unsigned short s_w[24576];  // 48 KB: fw1B | fw2B frags
    __shared__ short s_h1[N_ * F_];        // 16 KB, XOR-chunk swizzle
    __shared__ float s_scale[2][N_];
    __shared__ int   s_nb[2][N_];
    __shared__ float s_red[4][F_];

    const int tid  = threadIdx.x;
    const int w    = tid >> 6;
    const int l    = tid & 63;
    const int quad = l >> 4;
    const int c0   = l & 15;
    const int rw   = w & 3;               // row group
    const int h    = w >> 2;              // tf half

    const int abase = blockIdx.x * APB;   // APB-aligned -> same molecule
    const int b     = abase >> 8;

    // ---- stage weights into LDS (once): 6 x uint4 per thread ----
    {
        const uint4* w1 = (const uint4*)fw1B;   // 1024 uint4
        const uint4* w2 = (const uint4*)fw2B;   // 2048 uint4
        uint4* dst = (uint4*)s_w;
        #pragma unroll
        for (int i = 0; i < 6; ++i) {
            const int idx = tid + i * 512;
            dst[idx] = (idx < 1024) ? w1[idx] : w2[idx - 1024];
        }
    }
    // ---- meta for atom 0 ----
    if (h == 0 && l < 16) {
        const int n = rw * 16 + l;
        const float r = r_ij[(size_t)abase * N_ + n];
        const float c = (r < 5.0f)
            ? 0.5f * (__cosf(r * 0.62831853071795865f) + 1.0f)
            : 0.0f;
        s_scale[0][n] = c * mask[(size_t)abase * N_ + n];
        s_nb[0][n]    = nbrs[(size_t)abase * N_ + n];
    }
    // ---- A-tile prefetch for atom 0 ----
    float4 pf[4];
    {
        const float* base = f_ij + (size_t)abase * (N_ * G_)
                          + (size_t)(rw * 16 + c0) * G_ + quad * 8;
        pf[0] = *(const float4*)(base);
        pf[1] = *(const float4*)(base + 4);
        pf[2] = *(const float4*)(base + 32);
        pf[3] = *(const float4*)(base + 36);
    }
    // hoisted biases (per-lane, loop-invariant)
    float fb1v[4], fb2v[4];
    #pragma unroll
    for (int t = 0; t < 4; ++t) {
        fb1v[t] = fb1[(h * 4 + t) * 16 + c0];
        fb2v[t] = fb2[(h * 4 + t) * 16 + c0];
    }
    __syncthreads();   // weights + meta(0) staged

    const short8* sw1 = (const short8*)s_w;            // 16 frags
    const short8* sw2 = (const short8*)(s_w + 8192);   // 32 frags
    const unsigned short* yb = ypre + (size_t)b * A_ * F_;

    for (int i = 0; i < APB; ++i) {
        const int atom = abase + i;
        const int buf  = i & 1;

        // convert prefetched A-tile to frags
        short8 a1[2];
        a1[0] = pack_bf8(pf[0], pf[1]);
        a1[1] = pack_bf8(pf[2], pf[3]);

        // ---- GEMM1 (half): h1[:, h*64 .. h*64+64) ----
        floatx4 acc1[4];
        #pragma unroll
        for (int t = 0; t < 4; ++t) acc1[t] = (floatx4){0.f,0.f,0.f,0.f};
        #pragma unroll
        for (int ks = 0; ks < 2; ++ks)
            #pragma unroll
            for (int t = 0; t < 4; ++t) {
                const int tf = h * 4 + t;
                acc1[t] = __builtin_amdgcn_mfma_f32_16x16x32_bf16(
                    a1[ks], sw1[(tf * 2 + ks) * 64 + l], acc1[t], 0, 0, 0);
            }

        // ---- prefetch atom i+1 (loads stay in flight across barriers) ----
        if (i + 1 < APB) {
            const float* base = f_ij + (size_t)(atom + 1) * (N_ * G_)
                              + (size_t)(rw * 16 + c0) * G_ + quad * 8;
            pf[0] = *(const float4*)(base);
            pf[1] = *(const float4*)(base + 4);
            pf[2] = *(const float4*)(base + 32);
            pf[3] = *(const float4*)(base + 36);
            if (h == 0 && l < 16) {
                const int n = rw * 16 + l;
                const float r = r_ij[(size_t)(atom + 1) * N_ + n];
                const float c = (r < 5.0f)
                    ? 0.5f * (__cosf(r * 0.62831853071795865f) + 1.0f)
                    : 0.0f;
                s_scale[buf ^ 1][n] = c * mask[(size_t)(atom + 1) * N_ + n];
                s_nb[buf ^ 1][n]    = nbrs[(size_t)(atom + 1) * N_ + n];
            }
        }

        // ---- ssp + bias -> s_h1 (bf16, chunk-XOR swizzle) ----
        #pragma unroll
        for (int t = 0; t < 4; ++t) {
            const int   tf    = h * 4 + t;
            const int   chunk = tf * 2 + (c0 >> 3);
            const int   o     = c0 & 7;
            #pragma unroll
            for (int r = 0; r < 4; ++r) {
                const int row_l = quad * 4 + r;
                const float v = ssp(acc1[t][r] + fb1v[t]);
                s_h1[(rw * 16 + row_l) * F_ + ((chunk ^ row_l) * 8) + o] =
                    (short)f2bf(v);
            }
        }
        __syncthreads();   // h1 ready

        // ---- GEMM2 (half) + gather ----
        short8 a2[4];
        #pragma unroll
        for (int ks = 0; ks < 4; ++ks)
            a2[ks] = *(const short8*)&s_h1[(rw * 16 + c0) * F_
                                           + (((ks * 4 + quad) ^ c0) * 8)];

        float scl[4];
        uint2 yv[4];
        #pragma unroll
        for (int r = 0; r < 4; ++r) {
            const int n = rw * 16 + quad * 4 + r;
            scl[r] = s_scale[buf][n];
            yv[r] = *(const uint2*)&yb[(size_t)s_nb[buf][n] * F_
                                       + c0 * 8 + h * 4];
        }

        floatx4 acc2[4];
        #pragma unroll
        for (int t = 0; t < 4; ++t) acc2[t] = (floatx4){0.f,0.f,0.f,0.f};
        #pragma unroll
        for (int ks = 0; ks < 4; ++ks)
            #pragma unroll
            for (int t = 0; t < 4; ++t) {
                const int tf = h * 4 + t;
                acc2[t] = __builtin_amdgcn_mfma_f32_16x16x32_bf16(
                    a2[ks], sw2[(tf * 4 + ks) * 64 + l], acc2[t], 0, 0, 0);
            }

        // ---- aggregate ----
        float part[4];
        #pragma unroll
        for (int t = 0; t < 4; ++t) part[t] = 0.0f;
        #pragma unroll
        for (int r = 0; r < 4; ++r) {
            const unsigned d0 = yv[r].x, d1 = yv[r].y;
            part[0] = fmaf((acc2[0][r] + fb2v[0]) * scl[r], bf2f_lo(d0), part[0]);
            part[1] = fmaf((acc2[1][r] + fb2v[1]) * scl[r], bf2f_hi(d0), part[1]);
            part[2] = fmaf((acc2[2][r] + fb2v[2]) * scl[r], bf2f_lo(d1), part[2]);
            part[3] = fmaf((acc2[3][r] + fb2v[3]) * scl[r], bf2f_hi(d1), part[3]);
        }
        #pragma unroll
        for (int t = 0; t < 4; ++t) {
            part[t] += __shfl_xor(part[t], 16, 64);
            part[t] += __shfl_xor(part[t], 32, 64);
        }
        if (l < 16) {
            #pragma unroll
            for (int t = 0; t < 4; ++t)
                s_red[rw][(h * 4 + t) * 16 + l] = part[t];
        }
        __syncthreads();   // s_red ready

        if (tid < F_) {
            const float v = s_red[0][tid] + s_red[1][tid]
                          + s_red[2][tid] + s_red[3][tid];
            y_agg[(size_t)atom * F_ + tid] = (unsigned short)f2bf(v);
        }
        // next iteration's s_h1/s_red writes are separated from this
        // iteration's reads by the next h1-ready barrier.
    }
}

// ---------------------------------------------------------------------------
// K3: out = ssp(y_agg @ w_f2out + b_f2out). 64 blocks x 64 rows.
__global__ __launch_bounds__(256) void f2out_kernel(
    const unsigned short* __restrict__ y_agg,
    const unsigned short* __restrict__ woutB,
    const float* __restrict__ bias, float* __restrict__ out)
{
    const int tid = threadIdx.x;
    const int w = tid >> 6, l = tid & 63, quad = l >> 4, c0 = l & 15;
    const int row = blockIdx.x * 64 + w * 16 + c0;

    short8 a[4];
    #pragma unroll
    for (int ks = 0; ks < 4; ++ks)
        a[ks] = *(const short8*)&y_agg[(size_t)row * F_ + ks * 32 + quad * 8];

    const short8* W8 = (const short8*)woutB;
    floatx4 acc[8];
    #pragma unroll
    for (int tf = 0; tf < 8; ++tf) acc[tf] = (floatx4){0.f,0.f,0.f,0.f};
    #pragma unroll
    for (int ks = 0; ks < 4; ++ks)
        #pragma unroll
        for (int tf = 0; tf < 8; ++tf)
            acc[tf] = __builtin_amdgcn_mfma_f32_16x16x32_bf16(
                a[ks], W8[(tf * 4 + ks) * 64 + l], acc[tf], 0, 0, 0);

    #pragma unroll
    for (int tf = 0; tf < 8; ++tf) {
        const float bs = bias[tf * 16 + c0];
        #pragma unroll
        for (int r = 0; r < 4; ++r) {
            const int ro = blockIdx.x * 64 + w * 16 + quad * 4 + r;
            out[(size_t)ro * F_ + tf * 16 + c0] = ssp(acc[tf][r] + bs);
        }
    }
}

// ---------------------------------------------------------------------------
extern "C" void kernel_launch(void* const* d_in, const int* in_sizes, int n_in,
                              void* d_out, int out_size, void* d_ws, size_t ws_size,
                              hipStream_t stream) {
    const float* x        = (const float*)d_in[0];
    const float* r_ij     = (const float*)d_in[1];
    const float* f_ij     = (const float*)d_in[2];
    const int*   nbrs     = (const int*)  d_in[3];
    const float* mask     = (const float*)d_in[4];
    const float* fw1      = (const float*)d_in[5];
    const float* fb1      = (const float*)d_in[6];
    const float* fw2      = (const float*)d_in[7];
    const float* fb2      = (const float*)d_in[8];
    const float* w_in2f   = (const float*)d_in[9];
    const float* w_f2out  = (const float*)d_in[10];
    const float* b_f2out  = (const float*)d_in[11];
    float* out = (float*)d_out;

    // ws (shorts): ypre | fw1B | fw2B | winB | woutB | y_agg
    unsigned short* ypre  = (unsigned short*)d_ws;
    unsigned short* fw1B  = ypre  + (size_t)B_ * A_ * F_;   // 524288
    unsigned short* fw2B  = fw1B  + 8192;
    unsigned short* winB  = fw2B  + 16384;
    unsigned short* woutB = winB  + 16384;
    unsigned short* y_agg = woutB + 16384;

    k0_repack<<<56, 256, 0, stream>>>(
        fw1, fw2, w_in2f, w_f2out, fw1B, fw2B, winB, woutB);
    in2f_gemm<<<B_ * A_ / 64, 256, 0, stream>>>(x, winB, ypre);
    cfconv_kernel<<<B_ * A_ / APB, 512, 0, stream>>>(
        r_ij, f_ij, nbrs, mask, fb1, fb2, ypre, fw1B, fw2B, y_agg);
    f2out_kernel<<<B_ * A_ / 64, 256, 0, stream>>>(y_agg, woutB, b_f2out, out);
}

// Round 13
// 150.280 us; speedup vs baseline: 1.1311x; 1.0454x over previous
//
#include <hip/hip_runtime.h>
#include <hip/hip_bf16.h>
#include <math.h>

#define B_ 16
#define A_ 256
#define N_ 64
#define G_ 64
#define F_ 128
#define APB 8   // atoms per block (cfconv); grid = 4096/APB = 512 = 2 blocks/CU

typedef __attribute__((ext_vector_type(8))) short short8;
typedef __attribute__((ext_vector_type(4))) float floatx4;

__device__ __forceinline__ float ssp(float x) {
    // shifted softplus via native v_exp_f32 / v_log_f32
    const float t = __expf(-fabsf(x));
    return fmaxf(x, 0.0f) + __logf(1.0f + t) - 0.69314718055994531f;
}
// branch-free RNE fp32->bf16 (finite inputs only)
__device__ __forceinline__ unsigned f2bf(float f) {
    union { float f; unsigned u; } v; v.f = f;
    v.u += 0x7fffu + ((v.u >> 16) & 1u);
    return v.u >> 16;
}
__device__ __forceinline__ float bf2f_lo(unsigned d) {
    union { unsigned i; float f; } v; v.i = d << 16; return v.f;
}
__device__ __forceinline__ float bf2f_hi(unsigned d) {
    union { unsigned i; float f; } v; v.i = d & 0xffff0000u; return v.f;
}
__device__ __forceinline__ short8 pack_bf8(const float4& v0, const float4& v1) {
    short8 t;
    t[0] = (short)f2bf(v0.x); t[1] = (short)f2bf(v0.y);
    t[2] = (short)f2bf(v0.z); t[3] = (short)f2bf(v0.w);
    t[4] = (short)f2bf(v1.x); t[5] = (short)f2bf(v1.y);
    t[6] = (short)f2bf(v1.z); t[7] = (short)f2bf(v1.w);
    return t;
}

// ---------------------------------------------------------------------------
// K0: repack all four weights into MFMA B-frag order (bf16).
// frag layout [tf][ks][lane(64)][j(8)]: k = ks*32+(lane>>4)*8+j, f = tf*16+(lane&15)
__global__ __launch_bounds__(256) void k0_repack(
    const float* __restrict__ fw1, const float* __restrict__ fw2,
    const float* __restrict__ win, const float* __restrict__ wout,
    unsigned short* __restrict__ fw1B, unsigned short* __restrict__ fw2B,
    unsigned short* __restrict__ winB, unsigned short* __restrict__ woutB)
{
    int idx = blockIdx.x * 1024 + threadIdx.x * 4;
    #pragma unroll
    for (int u = 0; u < 4; ++u, ++idx) {
        if (idx < 8192) {                         // fw1: K=64
            const int j  = idx & 7;
            const int l  = (idx >> 3) & 63;
            const int ks = (idx >> 9) & 1;
            const int tf = idx >> 10;
            const int g  = ks * 32 + (l >> 4) * 8 + j;
            const int f  = tf * 16 + (l & 15);
            fw1B[idx] = (unsigned short)f2bf(fw1[g * F_ + f]);
        } else {                                  // K=128 packs
            const int i2  = (idx - 8192) & 16383;
            const int sel = (idx - 8192) >> 14;   // 0: fw2, 1: win, 2: wout
            const int j  = i2 & 7;
            const int l  = (i2 >> 3) & 63;
            const int ks = (i2 >> 9) & 3;
            const int tf = i2 >> 11;
            const int k  = ks * 32 + (l >> 4) * 8 + j;
            const int f  = tf * 16 + (l & 15);
            const float v = (sel == 0) ? fw2[k * F_ + f]
                          : (sel == 1) ? win[k * F_ + f]
                                       : wout[k * F_ + f];
            unsigned short* dst = (sel == 0) ? fw2B : (sel == 1) ? winB : woutB;
            dst[i2] = (unsigned short)f2bf(v);
        }
    }
}

// ---------------------------------------------------------------------------
// K1: ypre = bf16(x @ w_in2f), PERMUTED layout ypre[a*128 + c0*8 + tf].
// 256 blocks x 16 rows: wave w computes tf {2w, 2w+1}; 4x better CU coverage
// than the 64-block version (A-frag loads 4x redundant but L1/L2-hot).
__global__ __launch_bounds__(256) void in2f_gemm(
    const float* __restrict__ x, const unsigned short* __restrict__ winB,
    unsigned short* __restrict__ ypre)
{
    const int tid = threadIdx.x;
    const int w = tid >> 6, l = tid & 63, quad = l >> 4, c0 = l & 15;
    const int row = blockIdx.x * 16 + c0;

    short8 a[4];
    {
        const float* base = x + (size_t)row * F_ + quad * 8;
        #pragma unroll
        for (int ks = 0; ks < 4; ++ks)
            a[ks] = pack_bf8(*(const float4*)(base + ks * 32),
                             *(const float4*)(base + ks * 32 + 4));
    }

    const short8* W8 = (const short8*)winB;
    floatx4 acc[2];
    acc[0] = (floatx4){0.f,0.f,0.f,0.f};
    acc[1] = (floatx4){0.f,0.f,0.f,0.f};
    #pragma unroll
    for (int ks = 0; ks < 4; ++ks)
        #pragma unroll
        for (int t = 0; t < 2; ++t) {
            const int tf = w * 2 + t;
            acc[t] = __builtin_amdgcn_mfma_f32_16x16x32_bf16(
                a[ks], W8[(tf * 4 + ks) * 64 + l], acc[t], 0, 0, 0);
        }

    // permuted store: element (ro, col=tf*16+c0) -> ypre[ro*128 + c0*8 + tf];
    // tf pair (2w, 2w+1) adjacent -> one u32 store per r
    #pragma unroll
    for (int r = 0; r < 4; ++r) {
        const int ro = blockIdx.x * 16 + quad * 4 + r;
        const unsigned lo = f2bf(acc[0][r]);
        const unsigned hi = f2bf(acc[1][r]);
        *(unsigned*)&ypre[(size_t)ro * F_ + c0 * 8 + w * 2] = lo | (hi << 16);
    }
}

// ---------------------------------------------------------------------------
// K2: persistent block, 512 threads = 8 waves, APB atoms per block.
// Weights staged in LDS once; per-atom pipeline keeps next atom's f_ij +
// metadata loads in flight across both barriers (cp.async-style overlap).
// NOTE: byte-identical to the round-9/12 kernel (best measured: 47.2 us).
// Rounds 10/11 showed the acc-init and load ordering here are load-bearing:
// bias-folded acc init regressed 30% (forces accvgpr writes from live VGPRs).
__global__ __launch_bounds__(512) void cfconv_kernel(
    const float* __restrict__ r_ij, const float* __restrict__ f_ij,
    const int*   __restrict__ nbrs, const float* __restrict__ mask,
    const float* __restrict__ fb1,  const float* __restrict__ fb2,
    const unsigned short* __restrict__ ypre,
    const unsigned short* __restrict__ fw1B,
    const unsigned short* __restrict__ fw2B,
    unsigned short* __restrict__ y_agg)
{
    __shared__ unsigned short s_w[24576];  // 48 KB: fw1B | fw2B frags
    __shared__ short s_h1[N_ * F_];        // 16 KB, XOR-chunk swizzle
    __shared__ float s_scale[2][N_];
    __shared__ int   s_nb[2][N_];
    __shared__ float s_red[4][F_];

    const int tid  = threadIdx.x;
    const int w    = tid >> 6;
    const int l    = tid & 63;
    const int quad = l >> 4;
    const int c0   = l & 15;
    const int rw   = w & 3;               // row group
    const int h    = w >> 2;              // tf half

    const int abase = blockIdx.x * APB;   // APB-aligned -> same molecule
    const int b     = abase >> 8;

    // ---- stage weights into LDS (once): 6 x uint4 per thread ----
    {
        const uint4* w1 = (const uint4*)fw1B;   // 1024 uint4
        const uint4* w2 = (const uint4*)fw2B;   // 2048 uint4
        uint4* dst = (uint4*)s_w;
        #pragma unroll
        for (int i = 0; i < 6; ++i) {
            const int idx = tid + i * 512;
            dst[idx] = (idx < 1024) ? w1[idx] : w2[idx - 1024];
        }
    }
    // ---- meta for atom 0 ----
    if (h == 0 && l < 16) {
        const int n = rw * 16 + l;
        const float r = r_ij[(size_t)abase * N_ + n];
        const float c = (r < 5.0f)
            ? 0.5f * (__cosf(r * 0.62831853071795865f) + 1.0f)
            : 0.0f;
        s_scale[0][n] = c * mask[(size_t)abase * N_ + n];
        s_nb[0][n]    = nbrs[(size_t)abase * N_ + n];
    }
    // ---- A-tile prefetch for atom 0 ----
    float4 pf[4];
    {
        const float* base = f_ij + (size_t)abase * (N_ * G_)
                          + (size_t)(rw * 16 + c0) * G_ + quad * 8;
        pf[0] = *(const float4*)(base);
        pf[1] = *(const float4*)(base + 4);
        pf[2] = *(const float4*)(base + 32);
        pf[3] = *(const float4*)(base + 36);
    }
    // hoisted biases (per-lane, loop-invariant)
    float fb1v[4], fb2v[4];
    #pragma unroll
    for (int t = 0; t < 4; ++t) {
        fb1v[t] = fb1[(h * 4 + t) * 16 + c0];
        fb2v[t] = fb2[(h * 4 + t) * 16 + c0];
    }
    __syncthreads();   // weights + meta(0) staged

    const short8* sw1 = (const short8*)s_w;            // 16 frags
    const short8* sw2 = (const short8*)(s_w + 8192);   // 32 frags
    const unsigned short* yb = ypre + (size_t)b * A_ * F_;

    for (int i = 0; i < APB; ++i) {
        const int atom = abase + i;
        const int buf  = i & 1;

        // convert prefetched A-tile to frags
        short8 a1[2];
        a1[0] = pack_bf8(pf[0], pf[1]);
        a1[1] = pack_bf8(pf[2], pf[3]);

        // ---- GEMM1 (half): h1[:, h*64 .. h*64+64) ----
        floatx4 acc1[4];
        #pragma unroll
        for (int t = 0; t < 4; ++t) acc1[t] = (floatx4){0.f,0.f,0.f,0.f};
        #pragma unroll
        for (int ks = 0; ks < 2; ++ks)
            #pragma unroll
            for (int t = 0; t < 4; ++t) {
                const int tf = h * 4 + t;
                acc1[t] = __builtin_amdgcn_mfma_f32_16x16x32_bf16(
                    a1[ks], sw1[(tf * 2 + ks) * 64 + l], acc1[t], 0, 0, 0);
            }

        // ---- prefetch atom i+1 (loads stay in flight across barriers) ----
        if (i + 1 < APB) {
            const float* base = f_ij + (size_t)(atom + 1) * (N_ * G_)
                              + (size_t)(rw * 16 + c0) * G_ + quad * 8;
            pf[0] = *(const float4*)(base);
            pf[1] = *(const float4*)(base + 4);
            pf[2] = *(const float4*)(base + 32);
            pf[3] = *(const float4*)(base + 36);
            if (h == 0 && l < 16) {
                const int n = rw * 16 + l;
                const float r = r_ij[(size_t)(atom + 1) * N_ + n];
                const float c = (r < 5.0f)
                    ? 0.5f * (__cosf(r * 0.62831853071795865f) + 1.0f)
                    : 0.0f;
                s_scale[buf ^ 1][n] = c * mask[(size_t)(atom + 1) * N_ + n];
                s_nb[buf ^ 1][n]    = nbrs[(size_t)(atom + 1) * N_ + n];
            }
        }

        // ---- ssp + bias -> s_h1 (bf16, chunk-XOR swizzle) ----
        #pragma unroll
        for (int t = 0; t < 4; ++t) {
            const int   tf    = h * 4 + t;
            const int   chunk = tf * 2 + (c0 >> 3);
            const int   o     = c0 & 7;
            #pragma unroll
            for (int r = 0; r < 4; ++r) {
                const int row_l = quad * 4 + r;
                const float v = ssp(acc1[t][r] + fb1v[t]);
                s_h1[(rw * 16 + row_l) * F_ + ((chunk ^ row_l) * 8) + o] =
                    (short)f2bf(v);
            }
        }
        __syncthreads();   // h1 ready

        // ---- GEMM2 (half) + gather ----
        short8 a2[4];
        #pragma unroll
        for (int ks = 0; ks < 4; ++ks)
            a2[ks] = *(const short8*)&s_h1[(rw * 16 + c0) * F_
                                           + (((ks * 4 + quad) ^ c0) * 8)];

        float scl[4];
        uint2 yv[4];
        #pragma unroll
        for (int r = 0; r < 4; ++r) {
            const int n = rw * 16 + quad * 4 + r;
            scl[r] = s_scale[buf][n];
            yv[r] = *(const uint2*)&yb[(size_t)s_nb[buf][n] * F_
                                       + c0 * 8 + h * 4];
        }

        floatx4 acc2[4];
        #pragma unroll
        for (int t = 0; t < 4; ++t) acc2[t] = (floatx4){0.f,0.f,0.f,0.f};
        #pragma unroll
        for (int ks = 0; ks < 4; ++ks)
            #pragma unroll
            for (int t = 0; t < 4; ++t) {
                const int tf = h * 4 + t;
                acc2[t] = __builtin_amdgcn_mfma_f32_16x16x32_bf16(
                    a2[ks], sw2[(tf * 4 + ks) * 64 + l], acc2[t], 0, 0, 0);
            }

        // ---- aggregate ----
        float part[4];
        #pragma unroll
        for (int t = 0; t < 4; ++t) part[t] = 0.0f;
        #pragma unroll
        for (int r = 0; r < 4; ++r) {
            const unsigned d0 = yv[r].x, d1 = yv[r].y;
            part[0] = fmaf((acc2[0][r] + fb2v[0]) * scl[r], bf2f_lo(d0), part[0]);
            part[1] = fmaf((acc2[1][r] + fb2v[1]) * scl[r], bf2f_hi(d0), part[1]);
            part[2] = fmaf((acc2[2][r] + fb2v[2]) * scl[r], bf2f_lo(d1), part[2]);
            part[3] = fmaf((acc2[3][r] + fb2v[3]) * scl[r], bf2f_hi(d1), part[3]);
        }
        #pragma unroll
        for (int t = 0; t < 4; ++t) {
            part[t] += __shfl_xor(part[t], 16, 64);
            part[t] += __shfl_xor(part[t], 32, 64);
        }
        if (l < 16) {
            #pragma unroll
            for (int t = 0; t < 4; ++t)
                s_red[rw][(h * 4 + t) * 16 + l] = part[t];
        }
        __syncthreads();   // s_red ready

        if (tid < F_) {
            const float v = s_red[0][tid] + s_red[1][tid]
                          + s_red[2][tid] + s_red[3][tid];
            y_agg[(size_t)atom * F_ + tid] = (unsigned short)f2bf(v);
        }
        // next iteration's s_h1/s_red writes are separated from this
        // iteration's reads by the next h1-ready barrier.
    }
}

// ---------------------------------------------------------------------------
// K3: out = ssp(y_agg @ w_f2out + b_f2out). 256 blocks x 16 rows; wave w
// computes tf {2w, 2w+1} (4x better CU coverage than the 64-block version).
__global__ __launch_bounds__(256) void f2out_kernel(
    const unsigned short* __restrict__ y_agg,
    const unsigned short* __restrict__ woutB,
    const float* __restrict__ bias, float* __restrict__ out)
{
    const int tid = threadIdx.x;
    const int w = tid >> 6, l = tid & 63, quad = l >> 4, c0 = l & 15;
    const int row = blockIdx.x * 16 + c0;

    short8 a[4];
    #pragma unroll
    for (int ks = 0; ks < 4; ++ks)
        a[ks] = *(const short8*)&y_agg[(size_t)row * F_ + ks * 32 + quad * 8];

    const short8* W8 = (const short8*)woutB;
    floatx4 acc[2];
    acc[0] = (floatx4){0.f,0.f,0.f,0.f};
    acc[1] = (floatx4){0.f,0.f,0.f,0.f};
    #pragma unroll
    for (int ks = 0; ks < 4; ++ks)
        #pragma unroll
        for (int t = 0; t < 2; ++t) {
            const int tf = w * 2 + t;
            acc[t] = __builtin_amdgcn_mfma_f32_16x16x32_bf16(
                a[ks], W8[(tf * 4 + ks) * 64 + l], acc[t], 0, 0, 0);
        }

    #pragma unroll
    for (int t = 0; t < 2; ++t) {
        const int tf = w * 2 + t;
        const float bs = bias[tf * 16 + c0];
        #pragma unroll
        for (int r = 0; r < 4; ++r) {
            const int ro = blockIdx.x * 16 + quad * 4 + r;
            out[(size_t)ro * F_ + tf * 16 + c0] = ssp(acc[t][r] + bs);
        }
    }
}

// ---------------------------------------------------------------------------
extern "C" void kernel_launch(void* const* d_in, const int* in_sizes, int n_in,
                              void* d_out, int out_size, void* d_ws, size_t ws_size,
                              hipStream_t stream) {
    const float* x        = (const float*)d_in[0];
    const float* r_ij     = (const float*)d_in[1];
    const float* f_ij     = (const float*)d_in[2];
    const int*   nbrs     = (const int*)  d_in[3];
    const float* mask     = (const float*)d_in[4];
    const float* fw1      = (const float*)d_in[5];
    const float* fb1      = (const float*)d_in[6];
    const float* fw2      = (const float*)d_in[7];
    const float* fb2      = (const float*)d_in[8];
    const float* w_in2f   = (const float*)d_in[9];
    const float* w_f2out  = (const float*)d_in[10];
    const float* b_f2out  = (const float*)d_in[11];
    float* out = (float*)d_out;

    // ws (shorts): ypre | fw1B | fw2B | winB | woutB | y_agg
    unsigned short* ypre  = (unsigned short*)d_ws;
    unsigned short* fw1B  = ypre  + (size_t)B_ * A_ * F_;   // 524288
    unsigned short* fw2B  = fw1B  + 8192;
    unsigned short* winB  = fw2B  + 16384;
    unsigned short* woutB = winB  + 16384;
    unsigned short* y_agg = woutB + 16384;

    k0_repack<<<56, 256, 0, stream>>>(
        fw1, fw2, w_in2f, w_f2out, fw1B, fw2B, winB, woutB);
    in2f_gemm<<<B_ * A_ / 16, 256, 0, stream>>>(x, winB, ypre);
    cfconv_kernel<<<B_ * A_ / APB, 512, 0, stream>>>(
        r_ij, f_ij, nbrs, mask, fb1, fb2, ypre, fw1B, fw2B, y_agg);
    f2out_kernel<<<B_ * A_ / 16, 256, 0, stream>>>(y_agg, woutB, b_f2out, out);
}